// Round 11
// baseline (162.452 us; speedup 1.0000x reference)
//
#include <hip/hip_runtime.h>
#include <math.h>

// Problem constants (from reference)
#define N_NODES 10000
#define K_NB    32
#define D       256    // per-group input/output feature dim
#define XD      512    // x / t / out row stride (2 groups concatenated)

typedef __attribute__((ext_vector_type(8))) short  short8;  // 8 bf16 (4 VGPR) MFMA A/B frag
typedef __attribute__((ext_vector_type(4))) float  f32x4;   // MFMA C/D frag

__device__ __forceinline__ float clip1(float v) { return fminf(fmaxf(v, -1.f), 1.f); }

__device__ __forceinline__ unsigned int bf16_rne(float f) {   // RNE f32 -> bf16 bits
    unsigned int u = __float_as_uint(f);
    return (u + 0x7FFFu + ((u >> 16) & 1u)) >> 16;
}
__device__ __forceinline__ float bf16f(unsigned int h) { return __uint_as_float(h << 16); }
__device__ __forceinline__ float blo(unsigned int u) { return __uint_as_float(u << 16); }
__device__ __forceinline__ float bhif(unsigned int u) { return __uint_as_float(u & 0xFFFF0000u); }

// 8 consecutive-k fp32 -> hi/lo bf16 (Markidis split), packed 8x bf16 per uint4
__device__ __forceinline__ void cvt8(float4 A, float4 B, uint4& hi, uint4& lo) {
    const float v[8] = {A.x, A.y, A.z, A.w, B.x, B.y, B.z, B.w};
    unsigned int h[8], q[8];
    #pragma unroll
    for (int i = 0; i < 8; ++i) {
        h[i] = bf16_rne(v[i]);
        q[i] = bf16_rne(v[i] - bf16f(h[i]));
    }
    hi = make_uint4(h[0] | (h[1] << 16), h[2] | (h[3] << 16),
                    h[4] | (h[5] << 16), h[6] | (h[7] << 16));
    lo = make_uint4(q[0] | (q[1] << 16), q[2] | (q[3] << 16),
                    q[4] | (q[5] << 16), q[6] | (q[7] << 16));
}

// Kernel 0: one-time W -> bf16 hi/lo split (2 groups x 256x256, 8 elems/thread).
__global__ __launch_bounds__(256)
void conv_w(const float* __restrict__ W1, const float* __restrict__ W2,
            unsigned short* __restrict__ Whi, unsigned short* __restrict__ Wlo)
{
    const int u    = blockIdx.x * 256 + threadIdx.x;   // 0..16383 (oct index)
    const int gidx = u >> 13;                          // 8192 octs per group
    const int rem  = u & 8191;
    const float* __restrict__ W = gidx ? W2 : W1;
    const float4 f0 = *(const float4*)&W[rem * 8];
    const float4 f1 = *(const float4*)&W[rem * 8 + 4];
    uint4 hi, lo;
    cvt8(f0, f1, hi, lo);
    *(uint4*)&Whi[gidx * 65536 + rem * 8] = hi;
    *(uint4*)&Wlo[gidx * 65536 + rem * 8] = lo;
}

// Kernel 1: t16[row][g*256+o] = bf16( clip( (x_g@W^T)[row][o]*softmax(a)[o] ) )
// Split-precision bf16 MFMA: out ~= xh*wh + xl*wh + xh*wl (xl*wl dropped).
// Round-9 fix for latency-boundness (MfmaUtil 5%, VALU 12%, occ 46%):
//  - grid (625,2,2): col-tiles split across blockIdx.y -> wave owns 2 tiles,
//    10000 waves (~9.8/SIMD), 2x TLP.
//  - ALL 8 x-chunks prefetched before the kc loop (16 dwordx4 in flight,
//    fully unrolled -> static indices -> registers): the kc loop's critical
//    path is only L2-resident B loads + MFMA.
// C/D map: m89-verified col=lane&15, row=(lane>>4)*4+reg (validated r6-r8).
__global__ __launch_bounds__(256, 3)
void gemm_mfma(const float* __restrict__ x,
               const float* __restrict__ a1, const float* __restrict__ a2,
               const unsigned short* __restrict__ Whi,
               const unsigned short* __restrict__ Wlo,
               unsigned short* __restrict__ t16)
{
    const int g = blockIdx.z;
    const float* __restrict__ a = g ? a2 : a1;
    const int slab = blockIdx.x;            // 16-row slab, 0..624
    const int cz   = blockIdx.y;            // col half, 0..1
    const int tid = threadIdx.x;
    const int w   = tid >> 6;
    const int l   = tid & 63;

    __shared__ float fwL[D];
    __shared__ float red[16];

    // ---- softmax(a) over 256 (block == 256 threads), redundantly per block ----
    {
        float v = a[tid];
        float m = v;
        #pragma unroll
        for (int o = 32; o; o >>= 1) m = fmaxf(m, __shfl_xor(m, o));
        if ((tid & 63) == 0) red[tid >> 6] = m;
        __syncthreads();
        m = fmaxf(fmaxf(red[0], red[1]), fmaxf(red[2], red[3]));
        float e = expf(v - m);
        float s = e;
        #pragma unroll
        for (int o = 32; o; o >>= 1) s += __shfl_xor(s, o);
        if ((tid & 63) == 0) red[4 + (tid >> 6)] = s;
        __syncthreads();
        s = red[4] + red[5] + red[6] + red[7];
        fwL[tid] = e / s;
    }
    __syncthreads();                         // fwL visible to all waves (epilogue)

    const unsigned short* __restrict__ WhiG = Whi + (g << 16);
    const unsigned short* __restrict__ WloG = Wlo + (g << 16);

    const int arow = slab * 16 + (l & 15);   // this lane's A row
    const int koff = 8 * (l >> 4);           // this lane's k-slot base
    const int nt0  = cz * 8 + w * 2;         // this wave's 2 col-tiles

    // ---- prefetch ALL x chunks (8 kc x 8 floats/lane = 16 dwordx4 in flight) ----
    float4 pxa[8], pxb[8];
    const float* xrow = &x[(size_t)arow * XD + g * D + koff];
    #pragma unroll
    for (int kc = 0; kc < 8; ++kc) {
        pxa[kc] = *(const float4*)&xrow[kc * 32];
        pxb[kc] = *(const float4*)&xrow[kc * 32 + 4];
    }

    f32x4 acc[2];
    acc[0] = (f32x4){0.f, 0.f, 0.f, 0.f};
    acc[1] = (f32x4){0.f, 0.f, 0.f, 0.f};

    #pragma unroll
    for (int kc = 0; kc < 8; ++kc) {
        const int kbase = kc * 32 + koff;
        uint4 ahi, alo;
        cvt8(pxa[kc], pxb[kc], ahi, alo);
        const short8 ah = __builtin_bit_cast(short8, ahi);
        const short8 al = __builtin_bit_cast(short8, alo);

        // issue all 4 B-fragment loads (L2-resident) before the MFMAs
        const int brow0 = (nt0 + 0) * 16 + (l & 15);
        const int brow1 = (nt0 + 1) * 16 + (l & 15);
        const uint4 bh0u = *(const uint4*)&WhiG[brow0 * 256 + kbase];
        const uint4 bl0u = *(const uint4*)&WloG[brow0 * 256 + kbase];
        const uint4 bh1u = *(const uint4*)&WhiG[brow1 * 256 + kbase];
        const uint4 bl1u = *(const uint4*)&WloG[brow1 * 256 + kbase];
        const short8 bh0 = __builtin_bit_cast(short8, bh0u);
        const short8 bl0 = __builtin_bit_cast(short8, bl0u);
        const short8 bh1 = __builtin_bit_cast(short8, bh1u);
        const short8 bl1 = __builtin_bit_cast(short8, bl1u);

        // two independent 3-chains
        acc[0] = __builtin_amdgcn_mfma_f32_16x16x32_bf16(ah, bh0, acc[0], 0, 0, 0);
        acc[1] = __builtin_amdgcn_mfma_f32_16x16x32_bf16(ah, bh1, acc[1], 0, 0, 0);
        acc[0] = __builtin_amdgcn_mfma_f32_16x16x32_bf16(al, bh0, acc[0], 0, 0, 0);
        acc[1] = __builtin_amdgcn_mfma_f32_16x16x32_bf16(al, bh1, acc[1], 0, 0, 0);
        acc[0] = __builtin_amdgcn_mfma_f32_16x16x32_bf16(ah, bl0, acc[0], 0, 0, 0);
        acc[1] = __builtin_amdgcn_mfma_f32_16x16x32_bf16(ah, bl1, acc[1], 0, 0, 0);
    }

    // ---- epilogue: fw scale + hardtanh + bf16 store ----
    #pragma unroll
    for (int i = 0; i < 2; ++i) {
        const int   col = (nt0 + i) * 16 + (l & 15);
        const float fw  = fwL[col];
        #pragma unroll
        for (int r = 0; r < 4; ++r) {
            const int row = slab * 16 + (l >> 4) * 4 + r;
            t16[(size_t)row * XD + g * D + col] =
                (unsigned short)bf16_rne(clip1(acc[i][r] * fw));
        }
    }
}

// Kernel 2: SINGLE-PASS gather + Gaussian attention + aggregation, bf16 t.
// BYTE-IDENTICAL to round 9 (attribution: only gemm changes this round).
__global__ __launch_bounds__(256, 8)
void gat_aggregate(const unsigned short* __restrict__ t16,
                   const int* __restrict__ graph, float* __restrict__ out)
{
    const int n   = blockIdx.x;
    const int g   = blockIdx.y;
    const int tid = threadIdx.x;
    const int w   = tid >> 6;
    const int l   = tid & 63;

    __shared__ float part[4][D];    // per-wave partial weighted sums (4 KB)
    __shared__ float Ssh[4];        // per-wave partial exp-sums

    int rows[8];
    #pragma unroll
    for (int kk = 0; kk < 8; ++kk)
        rows[kk] = graph[(size_t)n * K_NB + (w + kk * 4)];

    const size_t gcol = (size_t)g * D + 4 * l;           // bf16 element index
    const uint2 ov = *(const uint2*)&t16[(size_t)n * XD + gcol];
    const float o0 = blo(ov.x), o1 = bhif(ov.x), o2 = blo(ov.y), o3 = bhif(ov.y);

    // batch all 8 gather loads before any use (8 outstanding 8B / lane)
    uint2 nbu[8];
    #pragma unroll
    for (int kk = 0; kk < 8; ++kk)
        nbu[kk] = *(const uint2*)&t16[(size_t)rows[kk] * XD + gcol];

    // unpack once; per-lane partial d2 for each of this wave's 8 k's
    float nf[8][4];
    float d2p[8];
    #pragma unroll
    for (int kk = 0; kk < 8; ++kk) {
        nf[kk][0] = blo(nbu[kk].x); nf[kk][1] = bhif(nbu[kk].x);
        nf[kk][2] = blo(nbu[kk].y); nf[kk][3] = bhif(nbu[kk].y);
        const float dx = o0 - nf[kk][0], dy = o1 - nf[kk][1];
        const float dz = o2 - nf[kk][2], dw = o3 - nf[kk][3];
        d2p[kk] = dx * dx + dy * dy + dz * dz + dw * dw;
    }

    // reduce-scatter over lane bits 0..2: lane l ends owning kk = l&7
    const bool b0 = l & 1, b1 = l & 2, b2 = l & 4;
    float u[4];
    #pragma unroll
    for (int i = 0; i < 4; ++i) {
        const float give = b0 ? d2p[2 * i] : d2p[2 * i + 1];
        const float keep = b0 ? d2p[2 * i + 1] : d2p[2 * i];
        u[i] = keep + __shfl_xor(give, 1);
    }
    float v[2];
    #pragma unroll
    for (int i = 0; i < 2; ++i) {
        const float give = b1 ? u[2 * i] : u[2 * i + 1];
        const float keep = b1 ? u[2 * i + 1] : u[2 * i];
        v[i] = keep + __shfl_xor(give, 2);
    }
    float d2 = (b2 ? v[1] : v[0]) + __shfl_xor(b2 ? v[0] : v[1], 4);
    // finish the 64-lane sum (kk = l&7 fixed, sum over the 8 lane-groups)
    d2 += __shfl_xor(d2, 8);
    d2 += __shfl_xor(d2, 16);
    d2 += __shfl_xor(d2, 32);

    const float e = __expf(-d2);          // ONE exp per lane (owns kk = l&7)

    // wave's exp-sum over its 8 k's (uniform in all lanes after 3 steps)
    float Sw = e;
    Sw += __shfl_xor(Sw, 1);
    Sw += __shfl_xor(Sw, 2);
    Sw += __shfl_xor(Sw, 4);

    // gather the 8 e's (ds_bpermute — LDS pipe) and accumulate
    const int base = l & 56;
    float4 p = make_float4(0.f, 0.f, 0.f, 0.f);
    #pragma unroll
    for (int kk = 0; kk < 8; ++kk) {
        const float ak = __shfl(e, base + kk);
        p.x += ak * nf[kk][0]; p.y += ak * nf[kk][1];
        p.z += ak * nf[kk][2]; p.w += ak * nf[kk][3];
    }

    *(float4*)&part[w][4 * l] = p;
    if (l == 0) Ssh[w] = Sw;
    __syncthreads();

    const float rS = 1.f / (Ssh[0] + Ssh[1] + Ssh[2] + Ssh[3]);
    const float y  = (part[0][tid] + part[1][tid] + part[2][tid] + part[3][tid]) * rS;
    out[(size_t)n * XD + (size_t)g * D + tid] = y;
}

extern "C" void kernel_launch(void* const* d_in, const int* in_sizes, int n_in,
                              void* d_out, int out_size, void* d_ws, size_t ws_size,
                              hipStream_t stream) {
    const float* x     = (const float*)d_in[0];
    const float* W1    = (const float*)d_in[1];
    const float* a1    = (const float*)d_in[2];
    const float* W2    = (const float*)d_in[3];
    const float* a2    = (const float*)d_in[4];
    const int*   graph = (const int*)d_in[5];
    float* out = (float*)d_out;

    // workspace layout: t16 bf16 (10.24 MB) | Whi (256 KB) | Wlo (256 KB)
    unsigned short* t16 = (unsigned short*)d_ws;
    unsigned short* Whi = t16 + (size_t)N_NODES * XD;
    unsigned short* Wlo = Whi + 2 * 65536;

    conv_w<<<64, 256, 0, stream>>>(W1, W2, Whi, Wlo);

    dim3 grid1(N_NODES / 16, 2, 2);                   // (625, colhalf, group)
    gemm_mfma<<<grid1, 256, 0, stream>>>(x, a1, a2, Whi, Wlo, t16);

    dim3 grid2(N_NODES, 2);
    gat_aggregate<<<grid2, 256, 0, stream>>>(t16, graph, out);
}

// Round 12
// 126.696 us; speedup vs baseline: 1.2822x; 1.2822x over previous
//
#include <hip/hip_runtime.h>
#include <math.h>

// Problem constants (from reference)
#define N_NODES 10000
#define K_NB    32
#define D       256    // per-group input/output feature dim
#define XD      512    // x / t / out row stride (2 groups concatenated)

typedef __attribute__((ext_vector_type(8))) short  short8;  // 8 bf16 (4 VGPR) MFMA A/B frag
typedef __attribute__((ext_vector_type(4))) float  f32x4;   // MFMA C/D frag

typedef __attribute__((address_space(1))) const unsigned int g_u32;
typedef __attribute__((address_space(3))) unsigned int       l_u32;

// explicit global->LDS DMA, 16B per lane (m97 path; scheduler cannot sink it)
__device__ __forceinline__ void gld_lds16(const void* g, void* l) {
    __builtin_amdgcn_global_load_lds((g_u32*)g, (l_u32*)l, 16, 0, 0);
}

__device__ __forceinline__ float clip1(float v) { return fminf(fmaxf(v, -1.f), 1.f); }

__device__ __forceinline__ unsigned int bf16_rne(float f) {   // RNE f32 -> bf16 bits
    unsigned int u = __float_as_uint(f);
    return (u + 0x7FFFu + ((u >> 16) & 1u)) >> 16;
}
__device__ __forceinline__ float bf16f(unsigned int h) { return __uint_as_float(h << 16); }
__device__ __forceinline__ float blo(unsigned int u) { return __uint_as_float(u << 16); }
__device__ __forceinline__ float bhif(unsigned int u) { return __uint_as_float(u & 0xFFFF0000u); }

// 8 consecutive-k fp32 -> hi/lo bf16 (Markidis split), packed 8x bf16 per uint4
__device__ __forceinline__ void cvt8(float4 A, float4 B, uint4& hi, uint4& lo) {
    const float v[8] = {A.x, A.y, A.z, A.w, B.x, B.y, B.z, B.w};
    unsigned int h[8], q[8];
    #pragma unroll
    for (int i = 0; i < 8; ++i) {
        h[i] = bf16_rne(v[i]);
        q[i] = bf16_rne(v[i] - bf16f(h[i]));
    }
    hi = make_uint4(h[0] | (h[1] << 16), h[2] | (h[3] << 16),
                    h[4] | (h[5] << 16), h[6] | (h[7] << 16));
    lo = make_uint4(q[0] | (q[1] << 16), q[2] | (q[3] << 16),
                    q[4] | (q[5] << 16), q[6] | (q[7] << 16));
}

// Kernel 0: one-time W -> bf16 hi/lo split (2 groups x 256x256, 8 elems/thread).
__global__ __launch_bounds__(256)
void conv_w(const float* __restrict__ W1, const float* __restrict__ W2,
            unsigned short* __restrict__ Whi, unsigned short* __restrict__ Wlo)
{
    const int u    = blockIdx.x * 256 + threadIdx.x;   // 0..16383 (oct index)
    const int gidx = u >> 13;                          // 8192 octs per group
    const int rem  = u & 8191;
    const float* __restrict__ W = gidx ? W2 : W1;
    const float4 f0 = *(const float4*)&W[rem * 8];
    const float4 f1 = *(const float4*)&W[rem * 8 + 4];
    uint4 hi, lo;
    cvt8(f0, f1, hi, lo);
    *(uint4*)&Whi[gidx * 65536 + rem * 8] = hi;
    *(uint4*)&Wlo[gidx * 65536 + rem * 8] = lo;
}

// Kernel 1: t16[row][g*256+o] = bf16( clip( (x_g@W^T)[row][o]*softmax(a)[o] ) )
// m97-style LDS pipeline sized for a SMALL gemm (round-11 lesson: hipcc sinks
// register prefetches — VGPR_Count=28 proved it; global_load_lds cannot sink).
//  - tile 32 rows x 128 cols; grid (313, 2, 2) = 1252 blocks (~5/CU resident,
//    ~20 waves/CU) — fixes the 1.2 waves/SIMD starvation of r6/r9/r11.
//  - per K-chunk (32): stage x raw fp32 (4KB) + Bhi/Blo bf16 (8KB each) via
//    global_load_lds; 2 barriers; cvt8 per lane; 12 MFMA per wave.
//  - LDS XOR swizzle BOTH-SIDES (rule 21): linear dest + inverse-swizzled
//    per-lane SOURCE granule + swizzled read:  A: kg^(row&7) (2-way, free);
//    B: kg^((row>>1)&3) (2-way).
// C/D map: m89-verified col=lane&15, row=(lane>>4)*4+reg (validated r6-r11).
__global__ __launch_bounds__(256, 6)
void gemm_mfma(const float* __restrict__ x,
               const float* __restrict__ a1, const float* __restrict__ a2,
               const unsigned short* __restrict__ Whi,
               const unsigned short* __restrict__ Wlo,
               unsigned short* __restrict__ t16)
{
    const int slab = blockIdx.x;            // 32-row slab, 0..312 (last 16 phantom)
    const int cz   = blockIdx.y;            // col half (128 cols)
    const int g    = blockIdx.z;
    const float* __restrict__ a = g ? a2 : a1;
    const int tid = threadIdx.x;
    const int w   = tid >> 6;
    const int l   = tid & 63;

    __shared__ float          As[32 * 32];        // 4KB  [row][k] fp32 (swz granules)
    __shared__ unsigned short Bhs[128 * 32];      // 8KB  [row][k] bf16 hi
    __shared__ unsigned short Bls[128 * 32];      // 8KB  bf16 lo
    __shared__ float fwL[D];
    __shared__ float red[16];

    // ---- softmax(a) over 256 (block == 256 threads), redundantly per block ----
    {
        float v = a[tid];
        float m = v;
        #pragma unroll
        for (int o = 32; o; o >>= 1) m = fmaxf(m, __shfl_xor(m, o));
        if ((tid & 63) == 0) red[tid >> 6] = m;
        __syncthreads();
        m = fmaxf(fmaxf(red[0], red[1]), fmaxf(red[2], red[3]));
        float e = expf(v - m);
        float s = e;
        #pragma unroll
        for (int o = 32; o; o >>= 1) s += __shfl_xor(s, o);
        if ((tid & 63) == 0) red[4 + (tid >> 6)] = s;
        __syncthreads();
        s = red[4] + red[5] + red[6] + red[7];
        fwL[tid] = e / s;
    }
    __syncthreads();

    const unsigned short* __restrict__ WhiG = Whi + (g << 16);
    const unsigned short* __restrict__ WloG = Wlo + (g << 16);

    // staging source addresses (per-thread, constant across chunks except k)
    const int arloc = tid >> 3;                       // A dest row 0..31
    int agrow = slab * 32 + arloc;                    // clamp phantom rows
    if (agrow > N_NODES - 1) agrow = N_NODES - 1;
    const int akg   = (tid & 7) ^ (arloc & 7);        // inverse-swizzled granule
    const float* aSrcBase = &x[(size_t)agrow * XD + g * D + akg * 4];

    const int brloc0 = tid >> 2;                      // B dest row (call 0) 0..63
    const int brloc1 = brloc0 + 64;                   // call 1 row
    const int bkg0   = (tid & 3) ^ ((brloc0 >> 1) & 3);
    const int bkg1   = (tid & 3) ^ ((brloc1 >> 1) & 3);
    const unsigned short* bhSrc0 = &WhiG[(cz * 128 + brloc0) * 256 + bkg0 * 8];
    const unsigned short* bhSrc1 = &WhiG[(cz * 128 + brloc1) * 256 + bkg1 * 8];
    const unsigned short* blSrc0 = &WloG[(cz * 128 + brloc0) * 256 + bkg0 * 8];
    const unsigned short* blSrc1 = &WloG[(cz * 128 + brloc1) * 256 + bkg1 * 8];

    const int woff = (tid >> 6) * 1024;               // wave-uniform LDS call base

    f32x4 acc[4];
    #pragma unroll
    for (int i = 0; i < 4; ++i) acc[i] = (f32x4){0.f, 0.f, 0.f, 0.f};

    const int arow_l = 16 * (w >> 1) + (l & 15);      // wave's A row in tile
    const int s      = l >> 4;                        // k-slot 0..3 (8 elems)
    const int ct0    = (w & 1) * 4;                   // wave's 4 col-tiles

    for (int kc = 0; kc < 8; ++kc) {
        // ---- stage chunk kc: 5 global_load_lds calls (DMA, cannot be sunk) ----
        gld_lds16(aSrcBase + kc * 32,  (char*)As  + woff);
        gld_lds16(bhSrc0   + kc * 32,  (char*)Bhs + woff);
        gld_lds16(bhSrc1   + kc * 32,  (char*)Bhs + 4096 + woff);
        gld_lds16(blSrc0   + kc * 32,  (char*)Bls + woff);
        gld_lds16(blSrc1   + kc * 32,  (char*)Bls + 4096 + woff);
        __syncthreads();   // compiler emits vmcnt(0) drain before barrier

        // ---- A fragment: 2 swizzled b128 reads -> cvt8 ----
        const int kg0 = (2 * s)     ^ (arow_l & 7);
        const int kg1 = (2 * s + 1) ^ (arow_l & 7);
        const float4 xa = *(const float4*)((const char*)As + arow_l * 128 + kg0 * 16);
        const float4 xb = *(const float4*)((const char*)As + arow_l * 128 + kg1 * 16);
        uint4 ahi, alo;
        cvt8(xa, xb, ahi, alo);
        const short8 ah = __builtin_bit_cast(short8, ahi);
        const short8 al = __builtin_bit_cast(short8, alo);

        #pragma unroll
        for (int i = 0; i < 4; ++i) {
            const int brow_l = (ct0 + i) * 16 + (l & 15);
            const int bkg    = s ^ ((brow_l >> 1) & 3);
            const short8 bh = __builtin_bit_cast(short8,
                *(const uint4*)((const char*)Bhs + brow_l * 64 + bkg * 16));
            const short8 bl = __builtin_bit_cast(short8,
                *(const uint4*)((const char*)Bls + brow_l * 64 + bkg * 16));
            acc[i] = __builtin_amdgcn_mfma_f32_16x16x32_bf16(ah, bh, acc[i], 0, 0, 0);
            acc[i] = __builtin_amdgcn_mfma_f32_16x16x32_bf16(al, bh, acc[i], 0, 0, 0);
            acc[i] = __builtin_amdgcn_mfma_f32_16x16x32_bf16(ah, bl, acc[i], 0, 0, 0);
        }
        __syncthreads();   // protect LDS from next chunk's overwrite
    }

    // ---- epilogue: fw scale + hardtanh + bf16 store ----
    #pragma unroll
    for (int i = 0; i < 4; ++i) {
        const int   col = cz * 128 + (ct0 + i) * 16 + (l & 15);
        const float fw  = fwL[col];
        #pragma unroll
        for (int r = 0; r < 4; ++r) {
            const int row = slab * 32 + 16 * (w >> 1) + (l >> 4) * 4 + r;
            if (row < N_NODES)
                t16[(size_t)row * XD + g * D + col] =
                    (unsigned short)bf16_rne(clip1(acc[i][r] * fw));
        }
    }
}

// Kernel 2: SINGLE-PASS gather + Gaussian attention + aggregation, bf16 t.
// BYTE-IDENTICAL to round 9 (attribution: only gemm changes this round).
__global__ __launch_bounds__(256, 8)
void gat_aggregate(const unsigned short* __restrict__ t16,
                   const int* __restrict__ graph, float* __restrict__ out)
{
    const int n   = blockIdx.x;
    const int g   = blockIdx.y;
    const int tid = threadIdx.x;
    const int w   = tid >> 6;
    const int l   = tid & 63;

    __shared__ float part[4][D];    // per-wave partial weighted sums (4 KB)
    __shared__ float Ssh[4];        // per-wave partial exp-sums

    int rows[8];
    #pragma unroll
    for (int kk = 0; kk < 8; ++kk)
        rows[kk] = graph[(size_t)n * K_NB + (w + kk * 4)];

    const size_t gcol = (size_t)g * D + 4 * l;           // bf16 element index
    const uint2 ov = *(const uint2*)&t16[(size_t)n * XD + gcol];
    const float o0 = blo(ov.x), o1 = bhif(ov.x), o2 = blo(ov.y), o3 = bhif(ov.y);

    // batch all 8 gather loads before any use (8 outstanding 8B / lane)
    uint2 nbu[8];
    #pragma unroll
    for (int kk = 0; kk < 8; ++kk)
        nbu[kk] = *(const uint2*)&t16[(size_t)rows[kk] * XD + gcol];

    // unpack once; per-lane partial d2 for each of this wave's 8 k's
    float nf[8][4];
    float d2p[8];
    #pragma unroll
    for (int kk = 0; kk < 8; ++kk) {
        nf[kk][0] = blo(nbu[kk].x); nf[kk][1] = bhif(nbu[kk].x);
        nf[kk][2] = blo(nbu[kk].y); nf[kk][3] = bhif(nbu[kk].y);
        const float dx = o0 - nf[kk][0], dy = o1 - nf[kk][1];
        const float dz = o2 - nf[kk][2], dw = o3 - nf[kk][3];
        d2p[kk] = dx * dx + dy * dy + dz * dz + dw * dw;
    }

    // reduce-scatter over lane bits 0..2: lane l ends owning kk = l&7
    const bool b0 = l & 1, b1 = l & 2, b2 = l & 4;
    float u[4];
    #pragma unroll
    for (int i = 0; i < 4; ++i) {
        const float give = b0 ? d2p[2 * i] : d2p[2 * i + 1];
        const float keep = b0 ? d2p[2 * i + 1] : d2p[2 * i];
        u[i] = keep + __shfl_xor(give, 1);
    }
    float v[2];
    #pragma unroll
    for (int i = 0; i < 2; ++i) {
        const float give = b1 ? u[2 * i] : u[2 * i + 1];
        const float keep = b1 ? u[2 * i + 1] : u[2 * i];
        v[i] = keep + __shfl_xor(give, 2);
    }
    float d2 = (b2 ? v[1] : v[0]) + __shfl_xor(b2 ? v[0] : v[1], 4);
    // finish the 64-lane sum (kk = l&7 fixed, sum over the 8 lane-groups)
    d2 += __shfl_xor(d2, 8);
    d2 += __shfl_xor(d2, 16);
    d2 += __shfl_xor(d2, 32);

    const float e = __expf(-d2);          // ONE exp per lane (owns kk = l&7)

    // wave's exp-sum over its 8 k's (uniform in all lanes after 3 steps)
    float Sw = e;
    Sw += __shfl_xor(Sw, 1);
    Sw += __shfl_xor(Sw, 2);
    Sw += __shfl_xor(Sw, 4);

    // gather the 8 e's (ds_bpermute — LDS pipe) and accumulate
    const int base = l & 56;
    float4 p = make_float4(0.f, 0.f, 0.f, 0.f);
    #pragma unroll
    for (int kk = 0; kk < 8; ++kk) {
        const float ak = __shfl(e, base + kk);
        p.x += ak * nf[kk][0]; p.y += ak * nf[kk][1];
        p.z += ak * nf[kk][2]; p.w += ak * nf[kk][3];
    }

    *(float4*)&part[w][4 * l] = p;
    if (l == 0) Ssh[w] = Sw;
    __syncthreads();

    const float rS = 1.f / (Ssh[0] + Ssh[1] + Ssh[2] + Ssh[3]);
    const float y  = (part[0][tid] + part[1][tid] + part[2][tid] + part[3][tid]) * rS;
    out[(size_t)n * XD + (size_t)g * D + tid] = y;
}

extern "C" void kernel_launch(void* const* d_in, const int* in_sizes, int n_in,
                              void* d_out, int out_size, void* d_ws, size_t ws_size,
                              hipStream_t stream) {
    const float* x     = (const float*)d_in[0];
    const float* W1    = (const float*)d_in[1];
    const float* a1    = (const float*)d_in[2];
    const float* W2    = (const float*)d_in[3];
    const float* a2    = (const float*)d_in[4];
    const int*   graph = (const int*)d_in[5];
    float* out = (float*)d_out;

    // workspace layout: t16 bf16 (10.24 MB) | Whi (256 KB) | Wlo (256 KB)
    unsigned short* t16 = (unsigned short*)d_ws;
    unsigned short* Whi = t16 + (size_t)N_NODES * XD;
    unsigned short* Wlo = Whi + 2 * 65536;

    conv_w<<<64, 256, 0, stream>>>(W1, W2, Whi, Wlo);

    dim3 grid1(313, 2, 2);                            // (32-row slab, colhalf, group)
    gemm_mfma<<<grid1, 256, 0, stream>>>(x, a1, a2, Whi, Wlo, t16);

    dim3 grid2(N_NODES, 2);
    gat_aggregate<<<grid2, 256, 0, stream>>>(t16, graph, out);
}